// Round 4
// baseline (498.621 us; speedup 1.0000x reference)
//
#include <hip/hip_runtime.h>
#include <hip/hip_bf16.h>

#define B 128
#define NPTS 2000
#define NHEAD 4
#define SPLITS 8
#define NEGV -1e8f
#define SCALE 0.0625f
#define PGRID 512
#define PBLK 512

typedef float f32x4 __attribute__((ext_vector_type(4)));
typedef __bf16 bf16x8 __attribute__((ext_vector_type(8)));

__device__ __forceinline__ float ftanh(float x) {
    float e = __expf(2.0f * x);
    return 1.0f - 2.0f / (e + 1.0f);
}
__device__ __forceinline__ float felu(float x) {
    return x > 0.0f ? x : __expf(x) - 1.0f;
}

// ---- fused preamble: (blocks < B) embed MLP + qtil ; (blocks >= B) pack Wref2 ----
__global__ __launch_bounds__(256) void k_prep(const float* __restrict__ raw,
        const float* __restrict__ E1, const float* __restrict__ b1,
        const float* __restrict__ E2, const float* __restrict__ b2,
        const float* __restrict__ E3, const float* __restrict__ b3,
        const float* __restrict__ v1,
        const float* __restrict__ Wq, const float* __restrict__ Wk,
        const float* __restrict__ wref2,
        float* __restrict__ qtilws, unsigned short* __restrict__ wpack) {
    int t = threadIdx.x;
    if (blockIdx.x >= B) {
        int p0 = ((blockIdx.x - B) * 256 + t) * 4;
        #pragma unroll
        for (int qq = 0; qq < 4; ++qq) {
            int p = p0 + qq;
            int j = p & 7, l = (p >> 3) & 63, fr = p >> 9;
            int kt = fr >> 4, nt = fr & 15;
            int k = kt * 32 + (l >> 4) * 8 + j;
            int n = nt * 16 + (l & 15);
            __bf16 h = (__bf16)wref2[k * 256 + n];
            wpack[p] = __builtin_bit_cast(unsigned short, h);
        }
        return;
    }
    int b = blockIdx.x;
    __shared__ float rs[6], h1[84], h2[64];
    __shared__ float q[256];
    __shared__ float qh[NHEAD][256];
    if (t < 6) rs[t] = raw[b * 6 + t];
    __syncthreads();
    if (t < 84) {
        float a = b1[t];
        #pragma unroll
        for (int i = 0; i < 6; ++i) a += rs[i] * E1[i * 84 + t];
        h1[t] = felu(a);
    }
    __syncthreads();
    if (t < 64) {
        float a = b2[t];
        #pragma unroll 4
        for (int i = 0; i < 84; ++i) a += h1[i] * E2[i * 64 + t];
        h2[t] = felu(a);
    }
    __syncthreads();
    if (t < 128) {
        float a = b3[t];
        #pragma unroll 4
        for (int i = 0; i < 64; ++i) a += h2[i] * E3[i * 128 + t];
        q[t] = v1[t];
        q[128 + t] = a;
    }
    __syncthreads();
    #pragma unroll
    for (int m = 0; m < NHEAD; ++m) {
        float acc = 0.f;
        #pragma unroll 4
        for (int d = 0; d < 256; ++d) acc += q[d] * Wq[(m * 256 + d) * 256 + t];
        qh[m][t] = acc;
    }
    __syncthreads();
    #pragma unroll
    for (int m = 0; m < NHEAD; ++m) {
        float acc = 0.f;
        #pragma unroll 4
        for (int e = 0; e < 256; ++e) acc += Wk[(m * 256 + t) * 256 + e] * qh[m][e];
        qtilws[(b * NHEAD + m) * 256 + t] = acc * SCALE;
    }
}

// ---- glimpse: 32-lane rows, branchless online softmax, reg ping-pong prefetch ----
__global__ __launch_bounds__(256, 4) void k_glimpse(const float* __restrict__ feat,
        const int* __restrict__ mask, const float* __restrict__ qtil,
        float* __restrict__ pmax, float* __restrict__ psum, float* __restrict__ pfbar) {
    int bid = blockIdx.x;
    int b = bid / SPLITS, sp = bid % SPLITS;
    int w = threadIdx.x >> 6;
    int h = (threadIdx.x >> 5) & 1;
    int c = threadIdx.x & 31;            // 8-float chunk
    const int sub = w * 2 + h;           // 0..7 row-streams
    const int base = sp * (NPTS / SPLITS);

    f32x4 qt[NHEAD][2];
    #pragma unroll
    for (int m = 0; m < NHEAD; ++m) {
        qt[m][0] = *(const f32x4*)(qtil + ((b * NHEAD + m) << 8) + c * 8);
        qt[m][1] = *(const f32x4*)(qtil + ((b * NHEAD + m) << 8) + c * 8 + 4);
    }
    float rmax[NHEAD], rsum[NHEAD];
    f32x4 fb[NHEAD][2];
    #pragma unroll
    for (int m = 0; m < NHEAD; ++m) {
        rmax[m] = -__builtin_huge_valf(); rsum[m] = 0.f;
        fb[m][0] = 0.f; fb[m][1] = 0.f;
    }

    f32x4 a0, a1; int mka;
    {
        int n = base + sub;
        const float* fp = feat + ((size_t)(b * NPTS + n) << 8) + c * 8;
        a0 = *(const f32x4*)fp; a1 = *(const f32x4*)(fp + 4);
        mka = mask[b * NPTS + n];
    }
    for (int it = 0; it < 32; ++it) {
        int rr2 = (it + 1) * 8 + sub;
        bool v2ok = rr2 < 250;
        int n2 = base + (v2ok ? rr2 : sub);
        const float* fp2 = feat + ((size_t)(b * NPTS + n2) << 8) + c * 8;
        f32x4 b0 = *(const f32x4*)fp2;
        f32x4 b1 = *(const f32x4*)(fp2 + 4);
        int mkb = v2ok ? mask[b * NPTS + n2] : 0;
        int rr = it * 8 + sub;
        int mk = (rr < 250) ? mka : 0;
        #pragma unroll
        for (int m = 0; m < NHEAD; ++m) {
            f32x4 tv = a0 * qt[m][0] + a1 * qt[m][1];
            float s = tv.x + tv.y + tv.z + tv.w;
            s += __shfl_xor(s, 1, 64);
            s += __shfl_xor(s, 2, 64);
            s += __shfl_xor(s, 4, 64);
            s += __shfl_xor(s, 8, 64);
            s += __shfl_xor(s, 16, 64);
            s = mk ? s : NEGV;
            float nm = fmaxf(rmax[m], s);
            float cr = __expf(rmax[m] - nm);
            float wt = __expf(s - nm);
            rsum[m] = rsum[m] * cr + wt;
            fb[m][0] = fb[m][0] * cr + wt * a0;
            fb[m][1] = fb[m][1] * cr + wt * a1;
            rmax[m] = nm;
        }
        a0 = b0; a1 = b1; mka = mkb;
    }

    __shared__ float sfb[8][256];
    __shared__ float smax[8][NHEAD], ssum[8][NHEAD];
    if (c == 0) {
        #pragma unroll
        for (int m = 0; m < NHEAD; ++m) { smax[sub][m] = rmax[m]; ssum[sub][m] = rsum[m]; }
    }
    int t = threadIdx.x;
    int pb = (b * SPLITS + sp) * NHEAD;
    #pragma unroll
    for (int m = 0; m < NHEAD; ++m) {
        __syncthreads();
        *(f32x4*)&sfb[sub][c * 8] = fb[m][0];
        *(f32x4*)&sfb[sub][c * 8 + 4] = fb[m][1];
        __syncthreads();
        float gmx = -__builtin_huge_valf();
        #pragma unroll
        for (int wg = 0; wg < 8; ++wg) gmx = fmaxf(gmx, smax[wg][m]);
        float acc = 0.f;
        #pragma unroll
        for (int wg = 0; wg < 8; ++wg) acc += sfb[wg][t] * __expf(smax[wg][m] - gmx);
        pfbar[(size_t)(pb + m) * 256 + t] = acc;
        if (t == 0) {
            float gs = 0.f;
            #pragma unroll
            for (int wg = 0; wg < 8; ++wg) gs += ssum[wg][m] * __expf(smax[wg][m] - gmx);
            pmax[pb + m] = gmx; psum[pb + m] = gs;
        }
    }
}

// ---- combine partials; g=fbar@Wv; query=sum g@Wo; q2=query@Wq2 ----
__global__ __launch_bounds__(256) void k_combine(const float* __restrict__ pmax,
        const float* __restrict__ psum, const float* __restrict__ pfbar,
        const float* __restrict__ Wv, const float* __restrict__ Wo,
        const float* __restrict__ Wq2, float* __restrict__ q2ws, float* __restrict__ outq) {
    int b = blockIdx.x, t = threadIdx.x;
    __shared__ float lpm[SPLITS][NHEAD], lps[SPLITS][NHEAD], gm[NHEAD], tm[NHEAD];
    __shared__ float fbar[NHEAD][256];
    __shared__ float g[NHEAD][256];
    __shared__ float qn[256];
    if (t < SPLITS * NHEAD) {
        int s = t >> 2, m = t & 3;
        lpm[s][m] = pmax[(b * SPLITS + s) * NHEAD + m];
        lps[s][m] = psum[(b * SPLITS + s) * NHEAD + m];
    }
    __syncthreads();
    if (t < NHEAD) {
        float gmx = -__builtin_huge_valf();
        for (int s = 0; s < SPLITS; ++s) gmx = fmaxf(gmx, lpm[s][t]);
        float ts = 0.f;
        for (int s = 0; s < SPLITS; ++s) ts += lps[s][t] * __expf(lpm[s][t] - gmx);
        gm[t] = gmx; tm[t] = ts;
    }
    __syncthreads();
    #pragma unroll
    for (int m = 0; m < NHEAD; ++m) {
        float fbv = 0.f;
        for (int s = 0; s < SPLITS; ++s)
            fbv += pfbar[(size_t)((b * SPLITS + s) * NHEAD + m) * 256 + t] * __expf(lpm[s][m] - gm[m]);
        fbar[m][t] = fbv / tm[m];
    }
    __syncthreads();
    #pragma unroll
    for (int m = 0; m < NHEAD; ++m) {
        float acc = 0.f;
        #pragma unroll 4
        for (int d = 0; d < 256; ++d) acc += fbar[m][d] * Wv[(m * 256 + d) * 256 + t];
        g[m][t] = acc;
    }
    __syncthreads();
    {
        float acc = 0.f;
        #pragma unroll
        for (int m = 0; m < NHEAD; ++m)
            #pragma unroll 4
            for (int e = 0; e < 256; ++e) acc += g[m][e] * Wo[(m * 256 + e) * 256 + t];
        qn[t] = acc;
        outq[b * 256 + t] = acc;
    }
    __syncthreads();
    {
        float acc = 0.f;
        #pragma unroll 4
        for (int d = 0; d < 256; ++d) acc += qn[d] * Wq2[d * 256 + t];
        q2ws[b * 256 + t] = acc;
    }
}

// ---- pointer head v4: 8 waves x 32-e-cols (16 frags = 64 VGPR), T14 ordering ----
__global__ __launch_bounds__(PBLK, 4) void k_pointer(const float* __restrict__ feat,
        const int* __restrict__ mask, const unsigned short* __restrict__ wpack,
        const float* __restrict__ q2, const float* __restrict__ vec2,
        float* __restrict__ u) {
    const int tid = threadIdx.x;
    const int w = tid >> 6, l = tid & 63;
    const int lr = l & 15, lg = l >> 4;
    // wave w owns e-cols w*32 .. w*32+31 (nt = 2w, 2w+1): 16 fragments, 64 VGPRs
    bf16x8 bf[8][2];
    #pragma unroll
    for (int kt = 0; kt < 8; ++kt)
        #pragma unroll
        for (int i = 0; i < 2; ++i) {
            int frag = kt * 16 + (w * 2 + i);
            bf[kt][i] = *(const bf16x8*)(wpack + ((frag << 6) + l) * 8);
        }
    float v2[2];
    #pragma unroll
    for (int i = 0; i < 2; ++i) v2[i] = vec2[w * 32 + i * 16 + lr];

    __shared__ char AB[16384];           // 2 x [16 rows][256 bf16], XOR-swizzled
    __shared__ float lu[2][8][16];
    const int srow = tid >> 5, sc = tid & 31;   // 32 threads/row, 16 B each
    const int swz = (srow & 7) << 4;
    const int NT = (B * NPTS) / 16;      // 16000

    int t0 = blockIdx.x;
    {   // prologue: stage tile t0 into buffer 0
        const float* gp = feat + ((size_t)(t0 * 16 + srow) << 8) + sc * 8;
        f32x4 pa = *(const f32x4*)gp, pb = *(const f32x4*)(gp + 4);
        bf16x8 h0;
        h0[0]=(__bf16)pa.x; h0[1]=(__bf16)pa.y; h0[2]=(__bf16)pa.z; h0[3]=(__bf16)pa.w;
        h0[4]=(__bf16)pb.x; h0[5]=(__bf16)pb.y; h0[6]=(__bf16)pb.z; h0[7]=(__bf16)pb.w;
        *(bf16x8*)(AB + srow * 512 + ((sc * 16) ^ swz)) = h0;
    }
    int cur = 0;
    int tprev = -1;
    for (int t = t0; t < NT; t += PGRID) {
        __syncthreads();                 // buf[cur] staged; prev lu[cur^1] written
        int tn = t + PGRID;
        bool has = tn < NT;
        int tl = has ? tn : t;
        // issue next-tile loads AFTER the barrier so they overlap compute (T14)
        const float* gp = feat + ((size_t)(tl * 16 + srow) << 8) + sc * 8;
        f32x4 pa = *(const f32x4*)gp, pb = *(const f32x4*)(gp + 4);
        // flush previous tile's u
        if (tprev >= 0 && tid < 16) {
            float tot = 0.f;
            #pragma unroll
            for (int ww = 0; ww < 8; ++ww) tot += lu[cur ^ 1][ww][tid];
            int pbb = tprev / 125;
            int pn = (tprev - pbb * 125) * 16 + tid;
            float uu = mask[pbb * NPTS + pn] ? 10.f * ftanh(tot) : NEGV;
            u[pbb * NPTS + pn] = uu;
        }
        // compute tile t from buf[cur]
        int b = t / 125;
        float q2v[2];
        #pragma unroll
        for (int i = 0; i < 2; ++i) q2v[i] = q2[b * 256 + w * 32 + i * 16 + lr];
        f32x4 acc[2];
        acc[0] = 0.f; acc[1] = 0.f;
        const char* rb = AB + cur * 8192 + lr * 512;
        const int rswz = (lr & 7) << 4;
        #pragma unroll
        for (int kt = 0; kt < 8; ++kt) {
            bf16x8 af = *(const bf16x8*)(rb + ((kt * 64 + lg * 16) ^ rswz));
            acc[0] = __builtin_amdgcn_mfma_f32_16x16x32_bf16(af, bf[kt][0], acc[0], 0, 0, 0);
            acc[1] = __builtin_amdgcn_mfma_f32_16x16x32_bf16(af, bf[kt][1], acc[1], 0, 0, 0);
        }
        float s0 = 0.f, s1 = 0.f, s2 = 0.f, s3 = 0.f;
        #pragma unroll
        for (int i = 0; i < 2; ++i) {
            float qv = q2v[i], vv = v2[i];
            s0 += ftanh(acc[i][0] + qv) * vv;
            s1 += ftanh(acc[i][1] + qv) * vv;
            s2 += ftanh(acc[i][2] + qv) * vv;
            s3 += ftanh(acc[i][3] + qv) * vv;
        }
        #pragma unroll
        for (int off = 1; off < 16; off <<= 1) {
            s0 += __shfl_xor(s0, off, 64);
            s1 += __shfl_xor(s1, off, 64);
            s2 += __shfl_xor(s2, off, 64);
            s3 += __shfl_xor(s3, off, 64);
        }
        if (lr == 0) {
            lu[cur][w][lg * 4 + 0] = s0; lu[cur][w][lg * 4 + 1] = s1;
            lu[cur][w][lg * 4 + 2] = s2; lu[cur][w][lg * 4 + 3] = s3;
        }
        // stage prefetched tile into buf[cur^1]
        if (has) {
            bf16x8 h0;
            h0[0]=(__bf16)pa.x; h0[1]=(__bf16)pa.y; h0[2]=(__bf16)pa.z; h0[3]=(__bf16)pa.w;
            h0[4]=(__bf16)pb.x; h0[5]=(__bf16)pb.y; h0[6]=(__bf16)pb.z; h0[7]=(__bf16)pb.w;
            *(bf16x8*)(AB + (cur ^ 1) * 8192 + srow * 512 + ((sc * 16) ^ swz)) = h0;
        }
        tprev = t; cur ^= 1;
    }
    __syncthreads();
    if (tprev >= 0 && tid < 16) {
        float tot = 0.f;
        #pragma unroll
        for (int ww = 0; ww < 8; ++ww) tot += lu[cur ^ 1][ww][tid];
        int pbb = tprev / 125;
        int pn = (tprev - pbb * 125) * 16 + tid;
        float uu = mask[pbb * NPTS + pn] ? 10.f * ftanh(tot) : NEGV;
        u[pbb * NPTS + pn] = uu;
    }
}

// ---- log-softmax with fixed max bound (|u| <= 10 or NEGV) ----
__global__ __launch_bounds__(256) void k_lse(const float* __restrict__ u, float* __restrict__ outp) {
    int b = blockIdx.x, t = threadIdx.x;
    float uv[8];
    int cnt = 0;
    float sm = 0.f;
    for (int i = t; i < NPTS; i += 256) {
        uv[cnt] = u[b * NPTS + i];
        sm += __expf(uv[cnt] - 10.f);
        ++cnt;
    }
    __shared__ float red[4];
    #pragma unroll
    for (int off = 1; off < 64; off <<= 1) sm += __shfl_xor(sm, off, 64);
    int w = t >> 6, l = t & 63;
    if (l == 0) red[w] = sm;
    __syncthreads();
    sm = red[0] + red[1] + red[2] + red[3];
    float lse = 10.f + __logf(sm);
    cnt = 0;
    for (int i = t; i < NPTS; i += 256) { outp[b * NPTS + i] = uv[cnt] - lse; ++cnt; }
}

extern "C" void kernel_launch(void* const* d_in, const int* in_sizes, int n_in,
                              void* d_out, int out_size, void* d_ws, size_t ws_size,
                              hipStream_t stream) {
    const float* feat = (const float*)d_in[0];
    const float* raw  = (const float*)d_in[1];
    const int*   mask = (const int*)d_in[2];
    const float* E1 = (const float*)d_in[3];
    const float* b1 = (const float*)d_in[4];
    const float* E2 = (const float*)d_in[5];
    const float* b2 = (const float*)d_in[6];
    const float* E3 = (const float*)d_in[7];
    const float* b3 = (const float*)d_in[8];
    const float* Wq = (const float*)d_in[9];
    const float* Wk = (const float*)d_in[10];
    const float* Wv = (const float*)d_in[11];
    const float* Wo = (const float*)d_in[12];
    const float* Wq2 = (const float*)d_in[13];
    const float* Wref2 = (const float*)d_in[14];
    const float* Vec2 = (const float*)d_in[15];
    const float* v1 = (const float*)d_in[16];
    float* out = (float*)d_out;

    char* ws = (char*)d_ws;
    float* qtilws  = (float*)(ws + 131072);        // 524288 B
    float* pmax    = (float*)(ws + 655360);        // 16384 B
    float* psum    = (float*)(ws + 671744);        // 16384 B
    float* pfbar   = (float*)(ws + 688128);        // 4194304 B
    float* q2ws    = (float*)(ws + 4882432);       // 131072 B
    unsigned short* wpack = (unsigned short*)(ws + 5013504);  // 131072 B
    float* uws     = (float*)(ws + 5144576);       // 1024000 B
    float* outq = out + B * NPTS;

    hipLaunchKernelGGL(k_prep, dim3(B + 64), dim3(256), 0, stream,
                       raw, E1, b1, E2, b2, E3, b3, v1, Wq, Wk, Wref2,
                       qtilws, wpack);
    hipLaunchKernelGGL(k_glimpse, dim3(B * SPLITS), dim3(256), 0, stream,
                       feat, mask, qtilws, pmax, psum, pfbar);
    hipLaunchKernelGGL(k_combine, dim3(B), dim3(256), 0, stream,
                       pmax, psum, pfbar, Wv, Wo, Wq2, q2ws, outq);
    hipLaunchKernelGGL(k_pointer, dim3(PGRID), dim3(PBLK), 0, stream,
                       feat, mask, wpack, q2ws, Vec2, uws);
    hipLaunchKernelGGL(k_lse, dim3(B), dim3(256), 0, stream, uws, out);
}

// Round 5
// 364.893 us; speedup vs baseline: 1.3665x; 1.3665x over previous
//
#include <hip/hip_runtime.h>
#include <hip/hip_bf16.h>

#define B 128
#define NPTS 2000
#define NHEAD 4
#define SPLITS 8
#define NEGV -1e8f
#define SCALE 0.0625f
#define PGRID 512
#define PBLK 512

typedef float f32x4 __attribute__((ext_vector_type(4)));
typedef __bf16 bf16x8 __attribute__((ext_vector_type(8)));

__device__ __forceinline__ float ftanh(float x) {
    float e = __expf(2.0f * x);
    return 1.0f - 2.0f / (e + 1.0f);
}
__device__ __forceinline__ float felu(float x) {
    return x > 0.0f ? x : __expf(x) - 1.0f;
}

// ---- fused preamble: (blocks < B) embed MLP + qtil ; (blocks >= B) pack Wref2 ----
__global__ __launch_bounds__(256) void k_prep(const float* __restrict__ raw,
        const float* __restrict__ E1, const float* __restrict__ b1,
        const float* __restrict__ E2, const float* __restrict__ b2,
        const float* __restrict__ E3, const float* __restrict__ b3,
        const float* __restrict__ v1,
        const float* __restrict__ Wq, const float* __restrict__ Wk,
        const float* __restrict__ wref2,
        float* __restrict__ qtilws, unsigned short* __restrict__ wpack) {
    int t = threadIdx.x;
    if (blockIdx.x >= B) {
        int p0 = ((blockIdx.x - B) * 256 + t) * 4;
        #pragma unroll
        for (int qq = 0; qq < 4; ++qq) {
            int p = p0 + qq;
            int j = p & 7, l = (p >> 3) & 63, fr = p >> 9;
            int kt = fr >> 4, nt = fr & 15;
            int k = kt * 32 + (l >> 4) * 8 + j;
            int n = nt * 16 + (l & 15);
            __bf16 h = (__bf16)wref2[k * 256 + n];
            wpack[p] = __builtin_bit_cast(unsigned short, h);
        }
        return;
    }
    int b = blockIdx.x;
    __shared__ float rs[6], h1[84], h2[64];
    __shared__ float q[256];
    __shared__ float qh[NHEAD][256];
    if (t < 6) rs[t] = raw[b * 6 + t];
    __syncthreads();
    if (t < 84) {
        float a = b1[t];
        #pragma unroll
        for (int i = 0; i < 6; ++i) a += rs[i] * E1[i * 84 + t];
        h1[t] = felu(a);
    }
    __syncthreads();
    if (t < 64) {
        float a = b2[t];
        #pragma unroll 4
        for (int i = 0; i < 84; ++i) a += h1[i] * E2[i * 64 + t];
        h2[t] = felu(a);
    }
    __syncthreads();
    if (t < 128) {
        float a = b3[t];
        #pragma unroll 4
        for (int i = 0; i < 64; ++i) a += h2[i] * E3[i * 128 + t];
        q[t] = v1[t];
        q[128 + t] = a;
    }
    __syncthreads();
    #pragma unroll
    for (int m = 0; m < NHEAD; ++m) {
        float acc = 0.f;
        #pragma unroll 4
        for (int d = 0; d < 256; ++d) acc += q[d] * Wq[(m * 256 + d) * 256 + t];
        qh[m][t] = acc;
    }
    __syncthreads();
    #pragma unroll
    for (int m = 0; m < NHEAD; ++m) {
        float acc = 0.f;
        #pragma unroll 4
        for (int e = 0; e < 256; ++e) acc += Wk[(m * 256 + t) * 256 + e] * qh[m][e];
        qtilws[(b * NHEAD + m) * 256 + t] = acc * SCALE;
    }
}

// ---- glimpse: 32-lane rows, branchless online softmax, reg ping-pong prefetch ----
__global__ __launch_bounds__(256, 4) void k_glimpse(const float* __restrict__ feat,
        const int* __restrict__ mask, const float* __restrict__ qtil,
        float* __restrict__ pmax, float* __restrict__ psum, float* __restrict__ pfbar) {
    int bid = blockIdx.x;
    int b = bid / SPLITS, sp = bid % SPLITS;
    int w = threadIdx.x >> 6;
    int h = (threadIdx.x >> 5) & 1;
    int c = threadIdx.x & 31;            // 8-float chunk
    const int sub = w * 2 + h;           // 0..7 row-streams
    const int base = sp * (NPTS / SPLITS);

    f32x4 qt[NHEAD][2];
    #pragma unroll
    for (int m = 0; m < NHEAD; ++m) {
        qt[m][0] = *(const f32x4*)(qtil + ((b * NHEAD + m) << 8) + c * 8);
        qt[m][1] = *(const f32x4*)(qtil + ((b * NHEAD + m) << 8) + c * 8 + 4);
    }
    float rmax[NHEAD], rsum[NHEAD];
    f32x4 fb[NHEAD][2];
    #pragma unroll
    for (int m = 0; m < NHEAD; ++m) {
        rmax[m] = -__builtin_huge_valf(); rsum[m] = 0.f;
        fb[m][0] = 0.f; fb[m][1] = 0.f;
    }

    f32x4 a0, a1; int mka;
    {
        int n = base + sub;
        const float* fp = feat + ((size_t)(b * NPTS + n) << 8) + c * 8;
        a0 = *(const f32x4*)fp; a1 = *(const f32x4*)(fp + 4);
        mka = mask[b * NPTS + n];
    }
    for (int it = 0; it < 32; ++it) {
        int rr2 = (it + 1) * 8 + sub;
        bool v2ok = rr2 < 250;
        int n2 = base + (v2ok ? rr2 : sub);
        const float* fp2 = feat + ((size_t)(b * NPTS + n2) << 8) + c * 8;
        f32x4 b0 = *(const f32x4*)fp2;
        f32x4 b1 = *(const f32x4*)(fp2 + 4);
        int mkb = v2ok ? mask[b * NPTS + n2] : 0;
        int rr = it * 8 + sub;
        int mk = (rr < 250) ? mka : 0;
        #pragma unroll
        for (int m = 0; m < NHEAD; ++m) {
            f32x4 tv = a0 * qt[m][0] + a1 * qt[m][1];
            float s = tv.x + tv.y + tv.z + tv.w;
            s += __shfl_xor(s, 1, 64);
            s += __shfl_xor(s, 2, 64);
            s += __shfl_xor(s, 4, 64);
            s += __shfl_xor(s, 8, 64);
            s += __shfl_xor(s, 16, 64);
            s = mk ? s : NEGV;
            float nm = fmaxf(rmax[m], s);
            float cr = __expf(rmax[m] - nm);
            float wt = __expf(s - nm);
            rsum[m] = rsum[m] * cr + wt;
            fb[m][0] = fb[m][0] * cr + wt * a0;
            fb[m][1] = fb[m][1] * cr + wt * a1;
            rmax[m] = nm;
        }
        a0 = b0; a1 = b1; mka = mkb;
    }

    __shared__ float sfb[8][256];
    __shared__ float smax[8][NHEAD], ssum[8][NHEAD];
    if (c == 0) {
        #pragma unroll
        for (int m = 0; m < NHEAD; ++m) { smax[sub][m] = rmax[m]; ssum[sub][m] = rsum[m]; }
    }
    int t = threadIdx.x;
    int pb = (b * SPLITS + sp) * NHEAD;
    #pragma unroll
    for (int m = 0; m < NHEAD; ++m) {
        __syncthreads();
        *(f32x4*)&sfb[sub][c * 8] = fb[m][0];
        *(f32x4*)&sfb[sub][c * 8 + 4] = fb[m][1];
        __syncthreads();
        float gmx = -__builtin_huge_valf();
        #pragma unroll
        for (int wg = 0; wg < 8; ++wg) gmx = fmaxf(gmx, smax[wg][m]);
        float acc = 0.f;
        #pragma unroll
        for (int wg = 0; wg < 8; ++wg) acc += sfb[wg][t] * __expf(smax[wg][m] - gmx);
        pfbar[(size_t)(pb + m) * 256 + t] = acc;
        if (t == 0) {
            float gs = 0.f;
            #pragma unroll
            for (int wg = 0; wg < 8; ++wg) gs += ssum[wg][m] * __expf(smax[wg][m] - gmx);
            pmax[pb + m] = gmx; psum[pb + m] = gs;
        }
    }
}

// ---- combine A: per-(b,m) softmax combine + g = fbar @ Wv[m], 16-stream ILP ----
__global__ __launch_bounds__(256) void k_combine_a(
        const float* __restrict__ pmax, const float* __restrict__ psum,
        const float* __restrict__ pfbar, const float* __restrict__ Wv,
        float* __restrict__ gws) {
    int bm = blockIdx.x;
    int b = bm >> 2, m = bm & 3;
    int t = threadIdx.x;
    __shared__ float lpm[SPLITS], lps[SPLITS];
    __shared__ float fbar[256];
    if (t < SPLITS) {
        lpm[t] = pmax[(b * SPLITS + t) * NHEAD + m];
        lps[t] = psum[(b * SPLITS + t) * NHEAD + m];
    }
    __syncthreads();
    float gmx = lpm[0];
    #pragma unroll
    for (int s = 1; s < SPLITS; ++s) gmx = fmaxf(gmx, lpm[s]);
    float ts = 0.f;
    #pragma unroll
    for (int s = 0; s < SPLITS; ++s) ts += lps[s] * __expf(lpm[s] - gmx);
    float fbv = 0.f;
    #pragma unroll
    for (int s = 0; s < SPLITS; ++s)
        fbv += pfbar[(size_t)((b * SPLITS + s) * NHEAD + m) * 256 + t] * __expf(lpm[s] - gmx);
    fbar[t] = fbv / ts;
    __syncthreads();
    // g[t] = sum_d fbar[d] * Wv[m][d][t], 16 independent accumulator streams
    const float* wv = Wv + (size_t)m * 65536 + t;
    float acc[16];
    #pragma unroll
    for (int i = 0; i < 16; ++i) acc[i] = 0.f;
    for (int dd = 0; dd < 16; ++dd) {
        #pragma unroll
        for (int i = 0; i < 16; ++i) {
            int d = i * 16 + dd;
            acc[i] += fbar[d] * wv[d * 256];
        }
    }
    float acct = 0.f;
    #pragma unroll
    for (int i = 0; i < 16; ++i) acct += acc[i];
    gws[bm * 256 + t] = acct;
}

// ---- combine B: query = sum_{m,e} g*Wo (K=1024, ILP-16); q2 = query@Wq2 (ILP-8) ----
__global__ __launch_bounds__(256) void k_combine_b(
        const float* __restrict__ gws, const float* __restrict__ Wo,
        const float* __restrict__ Wq2, float* __restrict__ q2ws,
        float* __restrict__ outq) {
    int b = blockIdx.x, t = threadIdx.x;
    __shared__ float gsh[1024];
    __shared__ float qn[256];
    #pragma unroll
    for (int i = 0; i < 4; ++i) gsh[i * 256 + t] = gws[b * 1024 + i * 256 + t];
    __syncthreads();
    {
        float acc[16];
        #pragma unroll
        for (int i = 0; i < 16; ++i) acc[i] = 0.f;
        for (int kk = 0; kk < 64; ++kk) {
            #pragma unroll
            for (int i = 0; i < 16; ++i) {
                int k = i * 64 + kk;
                acc[i] += gsh[k] * Wo[(size_t)k * 256 + t];
            }
        }
        float q = 0.f;
        #pragma unroll
        for (int i = 0; i < 16; ++i) q += acc[i];
        qn[t] = q;
        outq[b * 256 + t] = q;
    }
    __syncthreads();
    {
        float acc[8];
        #pragma unroll
        for (int i = 0; i < 8; ++i) acc[i] = 0.f;
        for (int kk = 0; kk < 32; ++kk) {
            #pragma unroll
            for (int i = 0; i < 8; ++i) {
                int d = i * 32 + kk;
                acc[i] += qn[d] * Wq2[(size_t)d * 256 + t];
            }
        }
        float q = 0.f;
        #pragma unroll
        for (int i = 0; i < 8; ++i) q += acc[i];
        q2ws[b * 256 + t] = q;
    }
}

// ---- pointer head v4: 8 waves x 32-e-cols (16 frags = 64 VGPR), T14 ordering ----
__global__ __launch_bounds__(PBLK, 4) void k_pointer(const float* __restrict__ feat,
        const int* __restrict__ mask, const unsigned short* __restrict__ wpack,
        const float* __restrict__ q2, const float* __restrict__ vec2,
        float* __restrict__ u) {
    const int tid = threadIdx.x;
    const int w = tid >> 6, l = tid & 63;
    const int lr = l & 15, lg = l >> 4;
    bf16x8 bf[8][2];
    #pragma unroll
    for (int kt = 0; kt < 8; ++kt)
        #pragma unroll
        for (int i = 0; i < 2; ++i) {
            int frag = kt * 16 + (w * 2 + i);
            bf[kt][i] = *(const bf16x8*)(wpack + ((frag << 6) + l) * 8);
        }
    float v2[2];
    #pragma unroll
    for (int i = 0; i < 2; ++i) v2[i] = vec2[w * 32 + i * 16 + lr];

    __shared__ char AB[16384];           // 2 x [16 rows][256 bf16], XOR-swizzled
    __shared__ float lu[2][8][16];
    const int srow = tid >> 5, sc = tid & 31;   // 32 threads/row, 16 B each
    const int swz = (srow & 7) << 4;
    const int NT = (B * NPTS) / 16;      // 16000

    int t0 = blockIdx.x;
    {   // prologue: stage tile t0 into buffer 0
        const float* gp = feat + ((size_t)(t0 * 16 + srow) << 8) + sc * 8;
        f32x4 pa = *(const f32x4*)gp, pb = *(const f32x4*)(gp + 4);
        bf16x8 h0;
        h0[0]=(__bf16)pa.x; h0[1]=(__bf16)pa.y; h0[2]=(__bf16)pa.z; h0[3]=(__bf16)pa.w;
        h0[4]=(__bf16)pb.x; h0[5]=(__bf16)pb.y; h0[6]=(__bf16)pb.z; h0[7]=(__bf16)pb.w;
        *(bf16x8*)(AB + srow * 512 + ((sc * 16) ^ swz)) = h0;
    }
    int cur = 0;
    int tprev = -1;
    for (int t = t0; t < NT; t += PGRID) {
        __syncthreads();                 // buf[cur] staged; prev lu[cur^1] written
        int tn = t + PGRID;
        bool has = tn < NT;
        int tl = has ? tn : t;
        // issue next-tile loads AFTER the barrier so they overlap compute (T14)
        const float* gp = feat + ((size_t)(tl * 16 + srow) << 8) + sc * 8;
        f32x4 pa = *(const f32x4*)gp, pb = *(const f32x4*)(gp + 4);
        // flush previous tile's u
        if (tprev >= 0 && tid < 16) {
            float tot = 0.f;
            #pragma unroll
            for (int ww = 0; ww < 8; ++ww) tot += lu[cur ^ 1][ww][tid];
            int pbb = tprev / 125;
            int pn = (tprev - pbb * 125) * 16 + tid;
            float uu = mask[pbb * NPTS + pn] ? 10.f * ftanh(tot) : NEGV;
            u[pbb * NPTS + pn] = uu;
        }
        // compute tile t from buf[cur]
        int b = t / 125;
        float q2v[2];
        #pragma unroll
        for (int i = 0; i < 2; ++i) q2v[i] = q2[b * 256 + w * 32 + i * 16 + lr];
        f32x4 acc[2];
        acc[0] = 0.f; acc[1] = 0.f;
        const char* rb = AB + cur * 8192 + lr * 512;
        const int rswz = (lr & 7) << 4;
        #pragma unroll
        for (int kt = 0; kt < 8; ++kt) {
            bf16x8 af = *(const bf16x8*)(rb + ((kt * 64 + lg * 16) ^ rswz));
            acc[0] = __builtin_amdgcn_mfma_f32_16x16x32_bf16(af, bf[kt][0], acc[0], 0, 0, 0);
            acc[1] = __builtin_amdgcn_mfma_f32_16x16x32_bf16(af, bf[kt][1], acc[1], 0, 0, 0);
        }
        float s0 = 0.f, s1 = 0.f, s2 = 0.f, s3 = 0.f;
        #pragma unroll
        for (int i = 0; i < 2; ++i) {
            float qv = q2v[i], vv = v2[i];
            s0 += ftanh(acc[i][0] + qv) * vv;
            s1 += ftanh(acc[i][1] + qv) * vv;
            s2 += ftanh(acc[i][2] + qv) * vv;
            s3 += ftanh(acc[i][3] + qv) * vv;
        }
        #pragma unroll
        for (int off = 1; off < 16; off <<= 1) {
            s0 += __shfl_xor(s0, off, 64);
            s1 += __shfl_xor(s1, off, 64);
            s2 += __shfl_xor(s2, off, 64);
            s3 += __shfl_xor(s3, off, 64);
        }
        if (lr == 0) {
            lu[cur][w][lg * 4 + 0] = s0; lu[cur][w][lg * 4 + 1] = s1;
            lu[cur][w][lg * 4 + 2] = s2; lu[cur][w][lg * 4 + 3] = s3;
        }
        // stage prefetched tile into buf[cur^1]
        if (has) {
            bf16x8 h0;
            h0[0]=(__bf16)pa.x; h0[1]=(__bf16)pa.y; h0[2]=(__bf16)pa.z; h0[3]=(__bf16)pa.w;
            h0[4]=(__bf16)pb.x; h0[5]=(__bf16)pb.y; h0[6]=(__bf16)pb.z; h0[7]=(__bf16)pb.w;
            *(bf16x8*)(AB + (cur ^ 1) * 8192 + srow * 512 + ((sc * 16) ^ swz)) = h0;
        }
        tprev = t; cur ^= 1;
    }
    __syncthreads();
    if (tprev >= 0 && tid < 16) {
        float tot = 0.f;
        #pragma unroll
        for (int ww = 0; ww < 8; ++ww) tot += lu[cur ^ 1][ww][tid];
        int pbb = tprev / 125;
        int pn = (tprev - pbb * 125) * 16 + tid;
        float uu = mask[pbb * NPTS + pn] ? 10.f * ftanh(tot) : NEGV;
        u[pbb * NPTS + pn] = uu;
    }
}

// ---- log-softmax with fixed max bound (|u| <= 10 or NEGV) ----
__global__ __launch_bounds__(256) void k_lse(const float* __restrict__ u, float* __restrict__ outp) {
    int b = blockIdx.x, t = threadIdx.x;
    float uv[8];
    int cnt = 0;
    float sm = 0.f;
    for (int i = t; i < NPTS; i += 256) {
        uv[cnt] = u[b * NPTS + i];
        sm += __expf(uv[cnt] - 10.f);
        ++cnt;
    }
    __shared__ float red[4];
    #pragma unroll
    for (int off = 1; off < 64; off <<= 1) sm += __shfl_xor(sm, off, 64);
    int w = t >> 6, l = t & 63;
    if (l == 0) red[w] = sm;
    __syncthreads();
    sm = red[0] + red[1] + red[2] + red[3];
    float lse = 10.f + __logf(sm);
    cnt = 0;
    for (int i = t; i < NPTS; i += 256) { outp[b * NPTS + i] = uv[cnt] - lse; ++cnt; }
}

extern "C" void kernel_launch(void* const* d_in, const int* in_sizes, int n_in,
                              void* d_out, int out_size, void* d_ws, size_t ws_size,
                              hipStream_t stream) {
    const float* feat = (const float*)d_in[0];
    const float* raw  = (const float*)d_in[1];
    const int*   mask = (const int*)d_in[2];
    const float* E1 = (const float*)d_in[3];
    const float* b1 = (const float*)d_in[4];
    const float* E2 = (const float*)d_in[5];
    const float* b2 = (const float*)d_in[6];
    const float* E3 = (const float*)d_in[7];
    const float* b3 = (const float*)d_in[8];
    const float* Wq = (const float*)d_in[9];
    const float* Wk = (const float*)d_in[10];
    const float* Wv = (const float*)d_in[11];
    const float* Wo = (const float*)d_in[12];
    const float* Wq2 = (const float*)d_in[13];
    const float* Wref2 = (const float*)d_in[14];
    const float* Vec2 = (const float*)d_in[15];
    const float* v1 = (const float*)d_in[16];
    float* out = (float*)d_out;

    char* ws = (char*)d_ws;
    float* qtilws  = (float*)(ws + 0);             // 524288 B
    float* pmax    = (float*)(ws + 524288);        // 16384 B
    float* psum    = (float*)(ws + 540672);        // 16384 B
    float* pfbar   = (float*)(ws + 557056);        // 4194304 B
    float* gws     = (float*)(ws + 4751360);       // 524288 B
    float* q2ws    = (float*)(ws + 5275648);       // 131072 B
    unsigned short* wpack = (unsigned short*)(ws + 5406720);  // 131072 B
    float* uws     = (float*)(ws + 5537792);       // 1024000 B
    float* outq = out + B * NPTS;

    hipLaunchKernelGGL(k_prep, dim3(B + 64), dim3(256), 0, stream,
                       raw, E1, b1, E2, b2, E3, b3, v1, Wq, Wk, Wref2,
                       qtilws, wpack);
    hipLaunchKernelGGL(k_glimpse, dim3(B * SPLITS), dim3(256), 0, stream,
                       feat, mask, qtilws, pmax, psum, pfbar);
    hipLaunchKernelGGL(k_combine_a, dim3(B * NHEAD), dim3(256), 0, stream,
                       pmax, psum, pfbar, Wv, gws);
    hipLaunchKernelGGL(k_combine_b, dim3(B), dim3(256), 0, stream,
                       gws, Wo, Wq2, q2ws, outq);
    hipLaunchKernelGGL(k_pointer, dim3(PGRID), dim3(PBLK), 0, stream,
                       feat, mask, wpack, q2ws, Vec2, uws);
    hipLaunchKernelGGL(k_lse, dim3(B), dim3(256), 0, stream, uws, out);
}

// Round 6
// 222.180 us; speedup vs baseline: 2.2442x; 1.6423x over previous
//
#include <hip/hip_runtime.h>
#include <hip/hip_bf16.h>

#define B 128
#define NPTS 2000
#define NHEAD 4
#define SPLITS 8
#define NEGV -1e8f
#define SCALE 0.0625f
#define PGRID 512
#define PBLK 512

typedef float f32x4 __attribute__((ext_vector_type(4)));
typedef __bf16 bf16x8 __attribute__((ext_vector_type(8)));

__device__ __forceinline__ float ftanh(float x) {
    float e = __expf(2.0f * x);
    return 1.0f - 2.0f / (e + 1.0f);
}
__device__ __forceinline__ float felu(float x) {
    return x > 0.0f ? x : __expf(x) - 1.0f;
}

// ---- embed MLP only: raw[b,6] -> ex[b,128]; query = [v1, ex] ----
__global__ __launch_bounds__(128) void k_embed(const float* __restrict__ raw,
        const float* __restrict__ E1, const float* __restrict__ b1,
        const float* __restrict__ E2, const float* __restrict__ b2,
        const float* __restrict__ E3, const float* __restrict__ b3,
        const float* __restrict__ v1, float* __restrict__ queryws) {
    int b = blockIdx.x, t = threadIdx.x;
    __shared__ float rs[6], h1[84], h2[64];
    if (t < 6) rs[t] = raw[b * 6 + t];
    __syncthreads();
    if (t < 84) {
        float a = b1[t];
        #pragma unroll
        for (int i = 0; i < 6; ++i) a += rs[i] * E1[i * 84 + t];
        h1[t] = felu(a);
    }
    __syncthreads();
    if (t < 64) {
        float a = b2[t];
        float a0 = 0.f, a1 = 0.f, a2 = 0.f, a3 = 0.f;
        for (int i = 0; i < 84; i += 4) {
            a0 += h1[i] * E2[i * 64 + t];
            a1 += h1[i + 1] * E2[(i + 1) * 64 + t];
            a2 += h1[i + 2] * E2[(i + 2) * 64 + t];
            a3 += h1[i + 3] * E2[(i + 3) * 64 + t];
        }
        h2[t] = felu(a + a0 + a1 + a2 + a3);
    }
    __syncthreads();
    {
        float a = b3[t];
        float a0 = 0.f, a1 = 0.f, a2 = 0.f, a3 = 0.f;
        for (int i = 0; i < 64; i += 4) {
            a0 += h2[i] * E3[i * 128 + t];
            a1 += h2[i + 1] * E3[(i + 1) * 128 + t];
            a2 += h2[i + 2] * E3[(i + 2) * 128 + t];
            a3 += h2[i + 3] * E3[(i + 3) * 128 + t];
        }
        queryws[b * 256 + t] = v1[t];
        queryws[b * 256 + 128 + t] = a + a0 + a1 + a2 + a3;
    }
}

// ---- per-(b,m): qh = q@Wq[m]; qtil = SCALE*Wk[m]@qh  (16-stream ILP); +pack blocks ----
__global__ __launch_bounds__(256) void k_qtil(const float* __restrict__ queryws,
        const float* __restrict__ Wq, const float* __restrict__ Wk,
        const float* __restrict__ wref2,
        float* __restrict__ qtilws, unsigned short* __restrict__ wpack) {
    int t = threadIdx.x;
    if (blockIdx.x >= B * NHEAD) {
        int p0 = ((blockIdx.x - B * NHEAD) * 256 + t) * 4;
        #pragma unroll
        for (int qq = 0; qq < 4; ++qq) {
            int p = p0 + qq;
            int j = p & 7, l = (p >> 3) & 63, fr = p >> 9;
            int kt = fr >> 4, nt = fr & 15;
            int k = kt * 32 + (l >> 4) * 8 + j;
            int n = nt * 16 + (l & 15);
            __bf16 h = (__bf16)wref2[k * 256 + n];
            wpack[p] = __builtin_bit_cast(unsigned short, h);
        }
        return;
    }
    int bm = blockIdx.x;
    int b = bm >> 2, m = bm & 3;
    __shared__ float q[256];
    __shared__ float qh[256];
    q[t] = queryws[b * 256 + t];
    __syncthreads();
    // qh[t] = sum_d q[d] * Wq[m][d][t]  — 16 independent accumulator streams
    {
        const float* wq = Wq + (size_t)m * 65536 + t;
        float acc[16];
        #pragma unroll
        for (int i = 0; i < 16; ++i) acc[i] = 0.f;
        for (int dd = 0; dd < 16; ++dd) {
            #pragma unroll
            for (int i = 0; i < 16; ++i) {
                int d = i * 16 + dd;
                acc[i] += q[d] * wq[(size_t)d * 256];
            }
        }
        float s = 0.f;
        #pragma unroll
        for (int i = 0; i < 16; ++i) s += acc[i];
        qh[t] = s;
    }
    __syncthreads();
    // qtil[t] = SCALE * sum_e Wk[m][t][e] * qh[e]  — row-major f32x4, 16 streams
    {
        const f32x4* wkr = (const f32x4*)(Wk + ((size_t)m * 256 + t) * 256);
        const f32x4* qh4 = (const f32x4*)qh;
        f32x4 a4[16];
        #pragma unroll
        for (int i = 0; i < 16; ++i) a4[i] = 0.f;
        for (int cc = 0; cc < 4; ++cc) {
            #pragma unroll
            for (int i = 0; i < 16; ++i) {
                int idx = i * 4 + cc;
                a4[i] += wkr[idx] * qh4[idx];
            }
        }
        f32x4 s4 = 0.f;
        #pragma unroll
        for (int i = 0; i < 16; ++i) s4 += a4[i];
        qtilws[bm * 256 + t] = (s4.x + s4.y + s4.z + s4.w) * SCALE;
    }
}

// ---- glimpse: 32-lane rows, branchless online softmax, reg ping-pong prefetch ----
__global__ __launch_bounds__(256, 4) void k_glimpse(const float* __restrict__ feat,
        const int* __restrict__ mask, const float* __restrict__ qtil,
        float* __restrict__ pmax, float* __restrict__ psum, float* __restrict__ pfbar) {
    int bid = blockIdx.x;
    int b = bid / SPLITS, sp = bid % SPLITS;
    int w = threadIdx.x >> 6;
    int h = (threadIdx.x >> 5) & 1;
    int c = threadIdx.x & 31;            // 8-float chunk
    const int sub = w * 2 + h;           // 0..7 row-streams
    const int base = sp * (NPTS / SPLITS);

    f32x4 qt[NHEAD][2];
    #pragma unroll
    for (int m = 0; m < NHEAD; ++m) {
        qt[m][0] = *(const f32x4*)(qtil + ((b * NHEAD + m) << 8) + c * 8);
        qt[m][1] = *(const f32x4*)(qtil + ((b * NHEAD + m) << 8) + c * 8 + 4);
    }
    float rmax[NHEAD], rsum[NHEAD];
    f32x4 fb[NHEAD][2];
    #pragma unroll
    for (int m = 0; m < NHEAD; ++m) {
        rmax[m] = -__builtin_huge_valf(); rsum[m] = 0.f;
        fb[m][0] = 0.f; fb[m][1] = 0.f;
    }

    f32x4 a0, a1; int mka;
    {
        int n = base + sub;
        const float* fp = feat + ((size_t)(b * NPTS + n) << 8) + c * 8;
        a0 = *(const f32x4*)fp; a1 = *(const f32x4*)(fp + 4);
        mka = mask[b * NPTS + n];
    }
    for (int it = 0; it < 32; ++it) {
        int rr2 = (it + 1) * 8 + sub;
        bool v2ok = rr2 < 250;
        int n2 = base + (v2ok ? rr2 : sub);
        const float* fp2 = feat + ((size_t)(b * NPTS + n2) << 8) + c * 8;
        f32x4 b0 = *(const f32x4*)fp2;
        f32x4 b1 = *(const f32x4*)(fp2 + 4);
        int mkb = v2ok ? mask[b * NPTS + n2] : 0;
        int rr = it * 8 + sub;
        int mk = (rr < 250) ? mka : 0;
        #pragma unroll
        for (int m = 0; m < NHEAD; ++m) {
            f32x4 tv = a0 * qt[m][0] + a1 * qt[m][1];
            float s = tv.x + tv.y + tv.z + tv.w;
            s += __shfl_xor(s, 1, 64);
            s += __shfl_xor(s, 2, 64);
            s += __shfl_xor(s, 4, 64);
            s += __shfl_xor(s, 8, 64);
            s += __shfl_xor(s, 16, 64);
            s = mk ? s : NEGV;
            float nm = fmaxf(rmax[m], s);
            float cr = __expf(rmax[m] - nm);
            float wt = __expf(s - nm);
            rsum[m] = rsum[m] * cr + wt;
            fb[m][0] = fb[m][0] * cr + wt * a0;
            fb[m][1] = fb[m][1] * cr + wt * a1;
            rmax[m] = nm;
        }
        a0 = b0; a1 = b1; mka = mkb;
    }

    __shared__ float sfb[8][256];
    __shared__ float smax[8][NHEAD], ssum[8][NHEAD];
    if (c == 0) {
        #pragma unroll
        for (int m = 0; m < NHEAD; ++m) { smax[sub][m] = rmax[m]; ssum[sub][m] = rsum[m]; }
    }
    int t = threadIdx.x;
    int pb = (b * SPLITS + sp) * NHEAD;
    #pragma unroll
    for (int m = 0; m < NHEAD; ++m) {
        __syncthreads();
        *(f32x4*)&sfb[sub][c * 8] = fb[m][0];
        *(f32x4*)&sfb[sub][c * 8 + 4] = fb[m][1];
        __syncthreads();
        float gmx = -__builtin_huge_valf();
        #pragma unroll
        for (int wg = 0; wg < 8; ++wg) gmx = fmaxf(gmx, smax[wg][m]);
        float acc = 0.f;
        #pragma unroll
        for (int wg = 0; wg < 8; ++wg) acc += sfb[wg][t] * __expf(smax[wg][m] - gmx);
        pfbar[(size_t)(pb + m) * 256 + t] = acc;
        if (t == 0) {
            float gs = 0.f;
            #pragma unroll
            for (int wg = 0; wg < 8; ++wg) gs += ssum[wg][m] * __expf(smax[wg][m] - gmx);
            pmax[pb + m] = gmx; psum[pb + m] = gs;
        }
    }
}

// ---- combine A: per-(b,m) softmax combine + g = fbar @ Wv[m], 16-stream ILP ----
__global__ __launch_bounds__(256) void k_combine_a(
        const float* __restrict__ pmax, const float* __restrict__ psum,
        const float* __restrict__ pfbar, const float* __restrict__ Wv,
        float* __restrict__ gws) {
    int bm = blockIdx.x;
    int b = bm >> 2, m = bm & 3;
    int t = threadIdx.x;
    __shared__ float lpm[SPLITS], lps[SPLITS];
    __shared__ float fbar[256];
    if (t < SPLITS) {
        lpm[t] = pmax[(b * SPLITS + t) * NHEAD + m];
        lps[t] = psum[(b * SPLITS + t) * NHEAD + m];
    }
    __syncthreads();
    float gmx = lpm[0];
    #pragma unroll
    for (int s = 1; s < SPLITS; ++s) gmx = fmaxf(gmx, lpm[s]);
    float ts = 0.f;
    #pragma unroll
    for (int s = 0; s < SPLITS; ++s) ts += lps[s] * __expf(lpm[s] - gmx);
    float fbv = 0.f;
    #pragma unroll
    for (int s = 0; s < SPLITS; ++s)
        fbv += pfbar[(size_t)((b * SPLITS + s) * NHEAD + m) * 256 + t] * __expf(lpm[s] - gmx);
    fbar[t] = fbv / ts;
    __syncthreads();
    const float* wv = Wv + (size_t)m * 65536 + t;
    float acc[16];
    #pragma unroll
    for (int i = 0; i < 16; ++i) acc[i] = 0.f;
    for (int dd = 0; dd < 16; ++dd) {
        #pragma unroll
        for (int i = 0; i < 16; ++i) {
            int d = i * 16 + dd;
            acc[i] += fbar[d] * wv[(size_t)d * 256];
        }
    }
    float acct = 0.f;
    #pragma unroll
    for (int i = 0; i < 16; ++i) acct += acc[i];
    gws[bm * 256 + t] = acct;
}

// ---- combine B: query = sum_{m,e} g*Wo (K=1024, ILP-16); q2 = query@Wq2 (ILP-8) ----
__global__ __launch_bounds__(256) void k_combine_b(
        const float* __restrict__ gws, const float* __restrict__ Wo,
        const float* __restrict__ Wq2, float* __restrict__ q2ws,
        float* __restrict__ outq) {
    int b = blockIdx.x, t = threadIdx.x;
    __shared__ float gsh[1024];
    __shared__ float qn[256];
    #pragma unroll
    for (int i = 0; i < 4; ++i) gsh[i * 256 + t] = gws[b * 1024 + i * 256 + t];
    __syncthreads();
    {
        float acc[16];
        #pragma unroll
        for (int i = 0; i < 16; ++i) acc[i] = 0.f;
        for (int kk = 0; kk < 64; ++kk) {
            #pragma unroll
            for (int i = 0; i < 16; ++i) {
                int k = i * 64 + kk;
                acc[i] += gsh[k] * Wo[(size_t)k * 256 + t];
            }
        }
        float q = 0.f;
        #pragma unroll
        for (int i = 0; i < 16; ++i) q += acc[i];
        qn[t] = q;
        outq[b * 256 + t] = q;
    }
    __syncthreads();
    {
        float acc[8];
        #pragma unroll
        for (int i = 0; i < 8; ++i) acc[i] = 0.f;
        for (int kk = 0; kk < 32; ++kk) {
            #pragma unroll
            for (int i = 0; i < 8; ++i) {
                int d = i * 32 + kk;
                acc[i] += qn[d] * Wq2[(size_t)d * 256 + t];
            }
        }
        float q = 0.f;
        #pragma unroll
        for (int i = 0; i < 8; ++i) q += acc[i];
        q2ws[b * 256 + t] = q;
    }
}

// ---- pointer head v4: 8 waves x 32-e-cols (16 frags = 64 VGPR), T14 ordering ----
__global__ __launch_bounds__(PBLK, 4) void k_pointer(const float* __restrict__ feat,
        const int* __restrict__ mask, const unsigned short* __restrict__ wpack,
        const float* __restrict__ q2, const float* __restrict__ vec2,
        float* __restrict__ u) {
    const int tid = threadIdx.x;
    const int w = tid >> 6, l = tid & 63;
    const int lr = l & 15, lg = l >> 4;
    bf16x8 bf[8][2];
    #pragma unroll
    for (int kt = 0; kt < 8; ++kt)
        #pragma unroll
        for (int i = 0; i < 2; ++i) {
            int frag = kt * 16 + (w * 2 + i);
            bf[kt][i] = *(const bf16x8*)(wpack + ((frag << 6) + l) * 8);
        }
    float v2[2];
    #pragma unroll
    for (int i = 0; i < 2; ++i) v2[i] = vec2[w * 32 + i * 16 + lr];

    __shared__ char AB[16384];           // 2 x [16 rows][256 bf16], XOR-swizzled
    __shared__ float lu[2][8][16];
    const int srow = tid >> 5, sc = tid & 31;   // 32 threads/row, 16 B each
    const int swz = (srow & 7) << 4;
    const int NT = (B * NPTS) / 16;      // 16000

    int t0 = blockIdx.x;
    {   // prologue: stage tile t0 into buffer 0
        const float* gp = feat + ((size_t)(t0 * 16 + srow) << 8) + sc * 8;
        f32x4 pa = *(const f32x4*)gp, pb = *(const f32x4*)(gp + 4);
        bf16x8 h0;
        h0[0]=(__bf16)pa.x; h0[1]=(__bf16)pa.y; h0[2]=(__bf16)pa.z; h0[3]=(__bf16)pa.w;
        h0[4]=(__bf16)pb.x; h0[5]=(__bf16)pb.y; h0[6]=(__bf16)pb.z; h0[7]=(__bf16)pb.w;
        *(bf16x8*)(AB + srow * 512 + ((sc * 16) ^ swz)) = h0;
    }
    int cur = 0;
    int tprev = -1;
    for (int t = t0; t < NT; t += PGRID) {
        __syncthreads();                 // buf[cur] staged; prev lu[cur^1] written
        int tn = t + PGRID;
        bool has = tn < NT;
        int tl = has ? tn : t;
        // issue next-tile loads AFTER the barrier so they overlap compute (T14)
        const float* gp = feat + ((size_t)(tl * 16 + srow) << 8) + sc * 8;
        f32x4 pa = *(const f32x4*)gp, pb = *(const f32x4*)(gp + 4);
        // flush previous tile's u
        if (tprev >= 0 && tid < 16) {
            float tot = 0.f;
            #pragma unroll
            for (int ww = 0; ww < 8; ++ww) tot += lu[cur ^ 1][ww][tid];
            int pbb = tprev / 125;
            int pn = (tprev - pbb * 125) * 16 + tid;
            float uu = mask[pbb * NPTS + pn] ? 10.f * ftanh(tot) : NEGV;
            u[pbb * NPTS + pn] = uu;
        }
        // compute tile t from buf[cur]
        int b = t / 125;
        float q2v[2];
        #pragma unroll
        for (int i = 0; i < 2; ++i) q2v[i] = q2[b * 256 + w * 32 + i * 16 + lr];
        f32x4 acc[2];
        acc[0] = 0.f; acc[1] = 0.f;
        const char* rb = AB + cur * 8192 + lr * 512;
        const int rswz = (lr & 7) << 4;
        #pragma unroll
        for (int kt = 0; kt < 8; ++kt) {
            bf16x8 af = *(const bf16x8*)(rb + ((kt * 64 + lg * 16) ^ rswz));
            acc[0] = __builtin_amdgcn_mfma_f32_16x16x32_bf16(af, bf[kt][0], acc[0], 0, 0, 0);
            acc[1] = __builtin_amdgcn_mfma_f32_16x16x32_bf16(af, bf[kt][1], acc[1], 0, 0, 0);
        }
        float s0 = 0.f, s1 = 0.f, s2 = 0.f, s3 = 0.f;
        #pragma unroll
        for (int i = 0; i < 2; ++i) {
            float qv = q2v[i], vv = v2[i];
            s0 += ftanh(acc[i][0] + qv) * vv;
            s1 += ftanh(acc[i][1] + qv) * vv;
            s2 += ftanh(acc[i][2] + qv) * vv;
            s3 += ftanh(acc[i][3] + qv) * vv;
        }
        #pragma unroll
        for (int off = 1; off < 16; off <<= 1) {
            s0 += __shfl_xor(s0, off, 64);
            s1 += __shfl_xor(s1, off, 64);
            s2 += __shfl_xor(s2, off, 64);
            s3 += __shfl_xor(s3, off, 64);
        }
        if (lr == 0) {
            lu[cur][w][lg * 4 + 0] = s0; lu[cur][w][lg * 4 + 1] = s1;
            lu[cur][w][lg * 4 + 2] = s2; lu[cur][w][lg * 4 + 3] = s3;
        }
        // stage prefetched tile into buf[cur^1]
        if (has) {
            bf16x8 h0;
            h0[0]=(__bf16)pa.x; h0[1]=(__bf16)pa.y; h0[2]=(__bf16)pa.z; h0[3]=(__bf16)pa.w;
            h0[4]=(__bf16)pb.x; h0[5]=(__bf16)pb.y; h0[6]=(__bf16)pb.z; h0[7]=(__bf16)pb.w;
            *(bf16x8*)(AB + (cur ^ 1) * 8192 + srow * 512 + ((sc * 16) ^ swz)) = h0;
        }
        tprev = t; cur ^= 1;
    }
    __syncthreads();
    if (tprev >= 0 && tid < 16) {
        float tot = 0.f;
        #pragma unroll
        for (int ww = 0; ww < 8; ++ww) tot += lu[cur ^ 1][ww][tid];
        int pbb = tprev / 125;
        int pn = (tprev - pbb * 125) * 16 + tid;
        float uu = mask[pbb * NPTS + pn] ? 10.f * ftanh(tot) : NEGV;
        u[pbb * NPTS + pn] = uu;
    }
}

// ---- log-softmax with fixed max bound (|u| <= 10 or NEGV) ----
__global__ __launch_bounds__(256) void k_lse(const float* __restrict__ u, float* __restrict__ outp) {
    int b = blockIdx.x, t = threadIdx.x;
    float uv[8];
    int cnt = 0;
    float sm = 0.f;
    for (int i = t; i < NPTS; i += 256) {
        uv[cnt] = u[b * NPTS + i];
        sm += __expf(uv[cnt] - 10.f);
        ++cnt;
    }
    __shared__ float red[4];
    #pragma unroll
    for (int off = 1; off < 64; off <<= 1) sm += __shfl_xor(sm, off, 64);
    int w = t >> 6, l = t & 63;
    if (l == 0) red[w] = sm;
    __syncthreads();
    sm = red[0] + red[1] + red[2] + red[3];
    float lse = 10.f + __logf(sm);
    cnt = 0;
    for (int i = t; i < NPTS; i += 256) { outp[b * NPTS + i] = uv[cnt] - lse; ++cnt; }
}

extern "C" void kernel_launch(void* const* d_in, const int* in_sizes, int n_in,
                              void* d_out, int out_size, void* d_ws, size_t ws_size,
                              hipStream_t stream) {
    const float* feat = (const float*)d_in[0];
    const float* raw  = (const float*)d_in[1];
    const int*   mask = (const int*)d_in[2];
    const float* E1 = (const float*)d_in[3];
    const float* b1 = (const float*)d_in[4];
    const float* E2 = (const float*)d_in[5];
    const float* b2 = (const float*)d_in[6];
    const float* E3 = (const float*)d_in[7];
    const float* b3 = (const float*)d_in[8];
    const float* Wq = (const float*)d_in[9];
    const float* Wk = (const float*)d_in[10];
    const float* Wv = (const float*)d_in[11];
    const float* Wo = (const float*)d_in[12];
    const float* Wq2 = (const float*)d_in[13];
    const float* Wref2 = (const float*)d_in[14];
    const float* Vec2 = (const float*)d_in[15];
    const float* v1 = (const float*)d_in[16];
    float* out = (float*)d_out;

    char* ws = (char*)d_ws;
    float* queryws = (float*)(ws + 0);             // 131072 B
    float* qtilws  = (float*)(ws + 131072);        // 524288 B
    float* pmax    = (float*)(ws + 655360);        // 16384 B
    float* psum    = (float*)(ws + 671744);        // 16384 B
    float* pfbar   = (float*)(ws + 688128);        // 4194304 B
    float* gws     = (float*)(ws + 4882432);       // 524288 B
    float* q2ws    = (float*)(ws + 5406720);       // 131072 B
    unsigned short* wpack = (unsigned short*)(ws + 5537792);  // 131072 B
    float* uws     = (float*)(ws + 5668864);       // 1024000 B
    float* outq = out + B * NPTS;

    hipLaunchKernelGGL(k_embed, dim3(B), dim3(128), 0, stream,
                       raw, E1, b1, E2, b2, E3, b3, v1, queryws);
    hipLaunchKernelGGL(k_qtil, dim3(B * NHEAD + 64), dim3(256), 0, stream,
                       queryws, Wq, Wk, Wref2, qtilws, wpack);
    hipLaunchKernelGGL(k_glimpse, dim3(B * SPLITS), dim3(256), 0, stream,
                       feat, mask, qtilws, pmax, psum, pfbar);
    hipLaunchKernelGGL(k_combine_a, dim3(B * NHEAD), dim3(256), 0, stream,
                       pmax, psum, pfbar, Wv, gws);
    hipLaunchKernelGGL(k_combine_b, dim3(B), dim3(256), 0, stream,
                       gws, Wo, Wq2, q2ws, outq);
    hipLaunchKernelGGL(k_pointer, dim3(PGRID), dim3(PBLK), 0, stream,
                       feat, mask, wpack, q2ws, Vec2, uws);
    hipLaunchKernelGGL(k_lse, dim3(B), dim3(256), 0, stream, uws, out);
}